// Round 11
// baseline (9421.421 us; speedup 1.0000x reference)
//
#include <hip/hip_runtime.h>
#include <stdint.h>

// ---------------------------------------------------------------------------
// ComplexApproximateBNN, round 14. R13 (best, 8597us) + ONE change: the A2
// half of the grid is software-pipelined one phase ahead. Dependency audit:
// A2 operand is >=2 phases old in phases h2/h3/h4 (p-4, p-2, p-2); only h1's
// A2 (h4_t) is p-1. So kq>=2 blocks wait done>=64(p-2) (already satisfied ->
// zero wait, run ahead), overlapping their 16MB of MALL-bypass A-loads +
// MFMA with the previous phase's combine tail. Changes:
//  - bid remap: kq = bid&3, nt = bid>>2 (group leaders are kq0 combiners).
//  - waits moved to phase START with role targets: kq0/kq1 -> rel>=p;
//    kq2/3 -> rel>=p-1 except h1 phases (rel>=p). rel=r certifies
//    done>=64(r-1). Leaders poll done, tick rel (R10 fanout).
//  - flags split per-kq (3 words/nt-line): run-ahead flags can't satisfy a
//    stale combiner wait. Combiner waits each flag >= p.
//  - parity-buffered partials (already in R13) tolerate the skew of 2.
// Everything else byte-identical to R13 (W-stationary 128 VGPR pinned,
// RMW-exchange writes, relaxed agent atomic loads, zero fences).
// ---------------------------------------------------------------------------

typedef __bf16 bf16;
typedef __attribute__((ext_vector_type(8))) __bf16 bf16x8;
typedef __attribute__((ext_vector_type(4))) float f32x4;

#define BATCH 64
#define TSTEPS 128
#define INDIM 512
#define XDIM 2048
#define OUTDIM 256
#define SLOTE ((size_t)BATCH * XDIM)  // elements per [b][2048] slot
#define NBLOCKS 256
#define GSTRIDE 64                    // u32 stride between counters = 256 B
#define PBPAR ((size_t)3 * BATCH * XDIM)  // one parity's partial region (f32)

__device__ __forceinline__ float apply_act(float h, int id) {
  switch (id) {
    case 0: return fmaxf(h, 0.0f);                       // relu
    case 1: return 1.0f / (1.0f + __expf(-h));           // sigmoid
    case 2: return tanhf(h);                             // tanh
    case 3: return h >= 0.0f ? h : 0.1f * h;             // leaky 0.1
    default: {                                           // selu
      const float sc = 1.0507009873554805f;
      const float al = 1.6732632423543772f;
      return h > 0.0f ? sc * h : sc * al * (__expf(h) - 1.0f);
    }
  }
}

// Agent-coherent 16B load as 2x8B relaxed atomic loads (proven R5/R9-R13).
__device__ __forceinline__ bf16x8 cload(const bf16* p) {
  union { unsigned long long q[2]; bf16x8 v; } u;
  const unsigned long long* qp = (const unsigned long long*)p;
  u.q[0] = __hip_atomic_load(qp, __ATOMIC_RELAXED, __HIP_MEMORY_SCOPE_AGENT);
  u.q[1] = __hip_atomic_load(qp + 1, __ATOMIC_RELAXED, __HIP_MEMORY_SCOPE_AGENT);
  return u.v;
}

// Coherent 8B store via atomic exchange (RMW at coherence point; proven R9).
__device__ __forceinline__ void cstore8(unsigned long long* p,
                                        unsigned long long v) {
  unsigned long long old = __hip_atomic_exchange(p, v, __ATOMIC_RELAXED,
                                                 __HIP_MEMORY_SCOPE_AGENT);
  asm volatile("" :: "v"(old));
}

__device__ __forceinline__ unsigned long long cload8(
    const unsigned long long* p) {
  return __hip_atomic_load(p, __ATOMIC_RELAXED, __HIP_MEMORY_SCOPE_AGENT);
}

// Phase-start wait. rel value r certifies done >= 64*(r-1) (all combiners of
// phase r-1 finished). Leaders (bid&31==0, always kq=0) poll done and tick
// their group's rel line; members poll rel (R10 storm-free fanout).
__device__ __forceinline__ void start_wait(unsigned* bars, int bid,
                                           unsigned tgt) {
  if (threadIdx.x == 0) {
    unsigned* done = bars + (size_t)8 * GSTRIDE;
    unsigned* rel = bars + (size_t)(9 + (bid >> 5)) * GSTRIDE;
    if ((bid & 31) == 0) {
      while (__hip_atomic_load(done, __ATOMIC_RELAXED,
                               __HIP_MEMORY_SCOPE_AGENT) < 64u * (tgt - 1u)) {
        __builtin_amdgcn_s_sleep(2);
      }
      __hip_atomic_fetch_add(rel, 1u, __ATOMIC_RELAXED,
                             __HIP_MEMORY_SCOPE_AGENT);
    } else {
      while (__hip_atomic_load(rel, __ATOMIC_RELAXED,
                               __HIP_MEMORY_SCOPE_AGENT) < tgt) {
        __builtin_amdgcn_s_sleep(2);
      }
    }
  }
  __syncthreads();
}

// One layer phase, W-stationary (R13 body). Block (nt = 32-col tile, kq =
// K-quarter; kq<2 -> A1, kq>=2 -> A2). kq>=1: publish partial (parity-
// buffered u64 exchanges) + per-kq flag. kq=0: MFMA own slice, wait 3 flags
// >= ph, read partials, combine lo + scale*hi + bias, act, ss, store h,
// tick done.
template <bool SCALE_A2, bool EMIT_SS, bool PLAIN_A1>
__device__ __forceinline__ void layer_phase(
    const int tid, const int nt, const int kq,
    const bf16* __restrict__ A1, const bf16* __restrict__ A2,
    const bf16x8 (&wf)[2][4], const float* __restrict__ bias,
    const int* __restrict__ acts, const float* __restrict__ ss_in,
    float* __restrict__ ss_out, bf16* __restrict__ outb,
    float* __restrict__ pbuf, unsigned* __restrict__ flags,
    unsigned* __restrict__ bars, const unsigned ph,
    float (&red)[8][64][33]) {
  const int lane = tid & 63;
  const int w = tid >> 6;        // 0..7 : 128-k slice within the K-quarter
  const int l15 = lane & 15;
  const int kb8 = (lane >> 4) * 8;
  const int q4 = lane >> 4;

  const bf16* As = (kq >= 2) ? A2 : A1;
  const int koff = (kq & 1) * 1024 + w * 128;
  const bf16* ap = As + (size_t)l15 * 2048 + koff + kb8;

  f32x4 acc[4][2];
  const f32x4 zero = {0.f, 0.f, 0.f, 0.f};
#pragma unroll
  for (int mt = 0; mt < 4; mt++) {
    acc[mt][0] = zero;
    acc[mt][1] = zero;
  }

  const bool plain = PLAIN_A1 && (kq < 2);
#pragma unroll
  for (int ks = 0; ks < 4; ks++) {
#pragma unroll
    for (int mt = 0; mt < 4; mt++) {
      const bf16* aptr = ap + (size_t)mt * 16 * 2048 + ks * 32;
      bf16x8 a = plain ? *(const bf16x8*)aptr : cload(aptr);
      acc[mt][0] = __builtin_amdgcn_mfma_f32_16x16x32_bf16(a, wf[0][ks], acc[mt][0], 0, 0, 0);
      acc[mt][1] = __builtin_amdgcn_mfma_f32_16x16x32_bf16(a, wf[1][ks], acc[mt][1], 0, 0, 0);
    }
  }

#pragma unroll
  for (int mt = 0; mt < 4; mt++)
#pragma unroll
    for (int n2 = 0; n2 < 2; n2++)
#pragma unroll
      for (int r = 0; r < 4; r++)
        red[w][mt * 16 + q4 * 4 + r][n2 * 16 + l15] = acc[mt][n2][r];
  __syncthreads();

  // per-thread ownership: row = tid>>3 (0..63), cols c4..c4+3
  const int row = tid >> 3;
  const int c4 = (tid & 7) * 4;
  float v[4];
#pragma unroll
  for (int j = 0; j < 4; j++) {
    float s = 0.f;
#pragma unroll
    for (int ww = 0; ww < 8; ww++) s += red[ww][row][c4 + j];
    v[j] = s;
  }

  float* pbase = pbuf + (size_t)(ph & 1) * PBPAR;
  const size_t pidx = ((size_t)row) * XDIM + nt * 32 + c4;
  if (kq != 0) {
    // writer: publish partial for this K-quarter (parity-buffered)
    float* pb = pbase + (size_t)(kq - 1) * BATCH * XDIM + pidx;
    union { float f[2]; unsigned long long u; } pk;
    pk.f[0] = v[0]; pk.f[1] = v[1];
    cstore8((unsigned long long*)pb, pk.u);
    pk.f[0] = v[2]; pk.f[1] = v[3];
    cstore8((unsigned long long*)(pb + 2), pk.u);
    __syncthreads();  // drain exchanges (vmcnt 0) before flag
    if (tid == 0) {
      __hip_atomic_fetch_add(flags + (size_t)nt * GSTRIDE + kq, 1u,
                             __ATOMIC_RELAXED, __HIP_MEMORY_SCOPE_AGENT);
    }
  } else {
    // combiner: wait each writer's per-kq flag >= ph
    if (tid == 0) {
      unsigned* f = flags + (size_t)nt * GSTRIDE;
      while (__hip_atomic_load(f + 1, __ATOMIC_RELAXED,
                               __HIP_MEMORY_SCOPE_AGENT) < ph) {
        __builtin_amdgcn_s_sleep(1);
      }
      while (__hip_atomic_load(f + 2, __ATOMIC_RELAXED,
                               __HIP_MEMORY_SCOPE_AGENT) < ph) {
        __builtin_amdgcn_s_sleep(1);
      }
      while (__hip_atomic_load(f + 3, __ATOMIC_RELAXED,
                               __HIP_MEMORY_SCOPE_AGENT) < ph) {
        __builtin_amdgcn_s_sleep(1);
      }
    }
    __syncthreads();
    float p1[4], p2[4], p3[4];
#pragma unroll
    for (int h = 0; h < 2; h++) {
      union { unsigned long long u; float f[2]; } u1, u2, u3;
      const unsigned long long* b1 =
          (const unsigned long long*)(pbase + pidx) + h;
      u1.u = cload8(b1);
      u2.u = cload8(b1 + (size_t)BATCH * XDIM / 2);
      u3.u = cload8(b1 + (size_t)BATCH * XDIM);
      p1[h * 2] = u1.f[0]; p1[h * 2 + 1] = u1.f[1];
      p2[h * 2] = u2.f[0]; p2[h * 2 + 1] = u2.f[1];
      p3[h * 2] = u3.f[0]; p3[h * 2 + 1] = u3.f[1];
    }
    float scale = 1.0f;
    if (SCALE_A2) {
      float ssv = __hip_atomic_load(ss_in + row, __ATOMIC_RELAXED,
                                    __HIP_MEMORY_SCOPE_AGENT);
      scale = 1.0f / fmaxf(sqrtf(ssv), 1e-12f);
    }
    const int cg = nt * 32 + c4;
    union { bf16 b[4]; unsigned long long u; } hk;
    float ssl = 0.f;
#pragma unroll
    for (int j = 0; j < 4; j++) {
      float lo = v[j] + p1[j];
      float hi = p2[j] + p3[j];
      float pre = (SCALE_A2 ? (lo + scale * hi) : (lo + hi)) + bias[cg + j];
      float av = apply_act(pre, acts[cg + j]);
      hk.b[j] = (bf16)av;
      ssl += av * av;
    }
    if (EMIT_SS) {
      ssl += __shfl_xor(ssl, 1);
      ssl += __shfl_xor(ssl, 2);
      ssl += __shfl_xor(ssl, 4);
      if ((tid & 7) == 0) atomicAdd(ss_out + row, ssl);
    }
    cstore8((unsigned long long*)(outb + (size_t)row * XDIM + cg), hk.u);
    __syncthreads();  // drain h exchanges + ss atomics before done-tick
    if (tid == 0) {
      __hip_atomic_fetch_add(bars + (size_t)8 * GSTRIDE, 1u, __ATOMIC_RELAXED,
                             __HIP_MEMORY_SCOPE_AGENT);
    }
  }
}

struct StepParams {
  bf16* h0;           // [128][64][2048], slices also reused as h4 slots 2..
  bf16* extra;        // h4 slots 0,1
  bf16* h1;
  bf16* h2a;
  bf16* h2b;
  bf16* h3;
  const bf16* whb;    // [4][2048][4096]
  const float* b_h;   // [4][2048]
  const int* acts;    // [5][2048]
  float* ss_li;       // [(T+1)*64]
  float* ss_bp;       // [(T+1)*64]
  float* pbuf;        // [2 parity][3][64][2048] f32 K-quarter partials
  unsigned* flags;    // [64*GSTRIDE] per-kq combine flags
  unsigned* bar;      // done counter + rel lines (zeroed), 32*GSTRIDE u32s
};

__global__ __launch_bounds__(512, 2) void step_loop(StepParams p) {
  __shared__ float red[8][64][33];
  const int tid = threadIdx.x;
  const int bid = blockIdx.x;
  const int kq = bid & 3;     // K-quarter (0,1: A1 halves; 2,3: A2 halves)
  const int nt = bid >> 2;    // 32-col n-tile
  const int lane = tid & 63;
  const int w = tid >> 6;
  const int l15 = lane & 15;
  const int kb8 = (lane >> 4) * 8;
  const size_t wstr = (size_t)XDIM * 2 * XDIM;

  // One-time W preload: 4 layers x 2 ntiles x 4 ksteps x bf16x8 = 128 VGPR.
  const bf16* wb = p.whb + (size_t)(nt * 32 + l15) * 4096 + kq * 1024 +
                   w * 128 + kb8;
  bf16x8 wf0[2][4], wf1[2][4], wf2[2][4], wf3[2][4];
#pragma unroll
  for (int n2 = 0; n2 < 2; n2++) {
#pragma unroll
    for (int ks = 0; ks < 4; ks++) {
      const bf16* q = wb + (size_t)n2 * 16 * 4096 + ks * 32;
      wf0[n2][ks] = *(const bf16x8*)q;
      wf1[n2][ks] = *(const bf16x8*)(q + wstr);
      wf2[n2][ks] = *(const bf16x8*)(q + 2 * wstr);
      wf3[n2][ks] = *(const bf16x8*)(q + 3 * wstr);
    }
  }

  const bool a2side = (kq >= 2);
  unsigned ph = 0;
  for (int t = 0; t < TSTEPS; t++) {
    // Pin W fragments: opaque asm touch defeats rematerialization/reload.
#pragma unroll
    for (int n2 = 0; n2 < 2; n2++)
#pragma unroll
      for (int ks = 0; ks < 4; ks++) {
        asm volatile("" : "+v"(wf0[n2][ks]), "+v"(wf1[n2][ks]),
                          "+v"(wf2[n2][ks]), "+v"(wf3[n2][ks]));
      }

    const bf16* h4t = (t < 2) ? p.extra + (size_t)t * SLOTE
                              : p.h0 + (size_t)(t - 2) * SLOTE;
    bf16* h4n = (t + 1 < 2) ? p.extra + (size_t)(t + 1) * SLOTE
                            : p.h0 + (size_t)(t - 1) * SLOTE;
    bf16* h2n = (t & 1) ? p.h2b : p.h2a;
    const bf16* h2o = (t & 1) ? p.h2a : p.h2b;

    // h1 = act([h0_t, norm(h4_t)] @ W0^T + b0)   (h4_t is p-1 -> no lag)
    ++ph;
    start_wait(p.bar, bid, ph);
    layer_phase<true, false, true>(tid, nt, kq, p.h0 + (size_t)t * SLOTE, h4t,
                                   wf0, p.b_h, p.acts + XDIM,
                                   p.ss_bp + t * BATCH, nullptr, p.h1,
                                   p.pbuf, p.flags, p.bar, ph, red);

    // h2 = act([h1, norm(h2_old)] @ W1^T + b1); emit ss_li[t+1]
    ++ph;
    start_wait(p.bar, bid, a2side ? ph - 1 : ph);  // h2_old is p-4
    layer_phase<true, true, false>(tid, nt, kq, p.h1, h2o, wf1, p.b_h + XDIM,
                                   p.acts + 2 * XDIM, p.ss_li + t * BATCH,
                                   p.ss_li + (t + 1) * BATCH, h2n,
                                   p.pbuf, p.flags, p.bar, ph, red);

    // h3 = act([h2, h1] @ W2^T + b2)
    ++ph;
    start_wait(p.bar, bid, a2side ? ph - 1 : ph);  // h1 is p-2
    layer_phase<false, false, false>(tid, nt, kq, h2n, p.h1, wf2,
                                     p.b_h + 2 * XDIM, p.acts + 3 * XDIM,
                                     nullptr, nullptr, p.h3,
                                     p.pbuf, p.flags, p.bar, ph, red);

    // h4 = act([h3, h2] @ W3^T + b3) -> slot t+1; emit ss_bp[t+1]
    ++ph;
    start_wait(p.bar, bid, a2side ? ph - 1 : ph);  // h2 is p-2
    layer_phase<false, true, false>(tid, nt, kq, p.h3, h2n, wf3,
                                    p.b_h + 3 * XDIM, p.acts + 4 * XDIM,
                                    nullptr, p.ss_bp + (t + 1) * BATCH, h4n,
                                    p.pbuf, p.flags, p.bar, ph, red);
  }
}

// h0 precompute: [8192,512]@[512->2048], rows r=b*128+t remapped to [t][b][n]
__global__ __launch_bounds__(256) void h0_gemm(
    const bf16* __restrict__ A, const bf16* __restrict__ W,
    const float* __restrict__ bias, const int* __restrict__ acts,
    bf16* __restrict__ outp) {
  const int tid = threadIdx.x;
  const int lane = tid & 63;
  const int wv = tid >> 6;
  const int wm = (wv & 1) * 32;
  const int wn = (wv >> 1) * 64;
  const int nblk = blockIdx.x * 128;
  const int mblk = blockIdx.y * 64;
  const int l15 = lane & 15;
  const int kb8 = (lane >> 4) * 8;

  f32x4 acc[2][4];
  const f32x4 zero = {0.f, 0.f, 0.f, 0.f};
#pragma unroll
  for (int i = 0; i < 2; i++)
#pragma unroll
    for (int j = 0; j < 4; j++) acc[i][j] = zero;

  for (int kt = 0; kt < INDIM; kt += 32) {
    bf16x8 a[2], b[4];
#pragma unroll
    for (int mt = 0; mt < 2; mt++) {
      int m = mblk + wm + mt * 16 + l15;
      a[mt] = *(const bf16x8*)(A + (size_t)m * INDIM + kt + kb8);
    }
#pragma unroll
    for (int nt = 0; nt < 4; nt++) {
      int n = nblk + wn + nt * 16 + l15;
      b[nt] = *(const bf16x8*)(W + (size_t)n * INDIM + kt + kb8);
    }
#pragma unroll
    for (int mt = 0; mt < 2; mt++)
#pragma unroll
      for (int nt = 0; nt < 4; nt++)
        acc[mt][nt] = __builtin_amdgcn_mfma_f32_16x16x32_bf16(a[mt], b[nt], acc[mt][nt], 0, 0, 0);
  }

#pragma unroll
  for (int mt = 0; mt < 2; mt++) {
#pragma unroll
    for (int nt = 0; nt < 4; nt++) {
      int n = nblk + wn + nt * 16 + l15;
      float bv = bias[n];
      int aid = acts[n];
#pragma unroll
      for (int rr = 0; rr < 4; rr++) {
        int m = wm + mt * 16 + (lane >> 4) * 4 + rr;
        float v = apply_act(acc[mt][nt][rr] + bv, aid);
        int rowg = mblk + m;  // = b*128 + t
        int bb = rowg >> 7;
        int tt = rowg & 127;
        outp[((size_t)tt * BATCH + bb) * XDIM + n] = (bf16)v;
      }
    }
  }
}

// batched output layer: for each t, y_t = act(h4slot(t+1) @ Wout^T + bout).
__global__ __launch_bounds__(256) void ybat_gemm(
    const bf16* __restrict__ extra, const bf16* __restrict__ h0,
    const bf16* __restrict__ Wout, const float* __restrict__ bout,
    const int* __restrict__ oact, float* __restrict__ out) {
  const int t = blockIdx.y;
  const int s = t + 1;
  const bf16* A = (s < 2) ? (extra + (size_t)s * SLOTE)
                          : (h0 + (size_t)(s - 2) * SLOTE);
  const int tid = threadIdx.x;
  const int lane = tid & 63;
  const int wv = tid >> 6;
  const int wm = (wv & 1) * 32;
  const int wn = (wv >> 1) * 64;
  const int nblk = blockIdx.x * 128;
  const int l15 = lane & 15;
  const int kb8 = (lane >> 4) * 8;

  f32x4 acc[2][4];
  const f32x4 zero = {0.f, 0.f, 0.f, 0.f};
#pragma unroll
  for (int i = 0; i < 2; i++)
#pragma unroll
    for (int j = 0; j < 4; j++) acc[i][j] = zero;

  for (int kt = 0; kt < XDIM; kt += 32) {
    bf16x8 a[2], b[4];
#pragma unroll
    for (int mt = 0; mt < 2; mt++) {
      int m = wm + mt * 16 + l15;
      a[mt] = *(const bf16x8*)(A + (size_t)m * XDIM + kt + kb8);
    }
#pragma unroll
    for (int nt = 0; nt < 4; nt++) {
      int n = nblk + wn + nt * 16 + l15;
      b[nt] = *(const bf16x8*)(Wout + (size_t)n * XDIM + kt + kb8);
    }
#pragma unroll
    for (int mt = 0; mt < 2; mt++)
#pragma unroll
      for (int nt = 0; nt < 4; nt++)
        acc[mt][nt] = __builtin_amdgcn_mfma_f32_16x16x32_bf16(a[mt], b[nt], acc[mt][nt], 0, 0, 0);
  }

#pragma unroll
  for (int mt = 0; mt < 2; mt++) {
#pragma unroll
    for (int nt = 0; nt < 4; nt++) {
      int n = nblk + wn + nt * 16 + l15;
      float bv = bout[n];
      int aid = oact[n];
#pragma unroll
      for (int rr = 0; rr < 4; rr++) {
        int b = wm + mt * 16 + (lane >> 4) * 4 + rr;  // batch row
        float v = apply_act(acc[mt][nt][rr] + bv, aid);
        out[((size_t)b * TSTEPS + t) * OUTDIM + n] = v;
      }
    }
  }
}

__global__ __launch_bounds__(256) void cvt_bf16(
    const float* __restrict__ in, bf16* __restrict__ out, int n4) {
  int i = blockIdx.x * 256 + threadIdx.x;
  if (i < n4) {
    float4 v = ((const float4*)in)[i];
    union { bf16 b[4]; unsigned long long u; } pk;
    pk.b[0] = (bf16)v.x;
    pk.b[1] = (bf16)v.y;
    pk.b[2] = (bf16)v.z;
    pk.b[3] = (bf16)v.w;
    ((unsigned long long*)out)[i] = pk.u;
  }
}

__global__ __launch_bounds__(256) void zero32(uint32_t* __restrict__ p, int n) {
  int i = blockIdx.x * 256 + threadIdx.x;
  if (i < n) p[i] = 0u;
}

extern "C" void kernel_launch(void* const* d_in, const int* in_sizes, int n_in,
                              void* d_out, int out_size, void* d_ws, size_t ws_size,
                              hipStream_t stream) {
  const float* x     = (const float*)d_in[0];   // [64,128,512]
  const float* W_in  = (const float*)d_in[1];   // [2048,512]
  const float* b_in  = (const float*)d_in[2];   // [2048]
  const float* W_h   = (const float*)d_in[3];   // [4,2048,4096]
  const float* b_h   = (const float*)d_in[4];   // [4,2048]
  const float* W_out = (const float*)d_in[5];   // [256,2048]
  const float* b_out = (const float*)d_in[6];   // [256]
  const int* act_ids = (const int*)d_in[7];     // [5,2048]
  const int* out_act = (const int*)d_in[8];     // [256]
  float* out = (float*)d_out;                   // [64,128,256]

  char* w = (char*)d_ws;
  bf16* xbf   = (bf16*)w; w += (size_t)BATCH * TSTEPS * INDIM * 2;   // 8 MB
  bf16* winb  = (bf16*)w; w += (size_t)XDIM * INDIM * 2;             // 2 MB
  bf16* whb   = (bf16*)w; w += (size_t)4 * XDIM * (2 * XDIM) * 2;    // 64 MB
  bf16* woutb = (bf16*)w; w += (size_t)OUTDIM * XDIM * 2;            // 1 MB
  bf16* h0    = (bf16*)w; w += (size_t)TSTEPS * SLOTE * 2;           // 32 MB (doubles as h4 slots 2..)
  bf16* h1    = (bf16*)w; w += SLOTE * 2;
  bf16* h3    = (bf16*)w; w += SLOTE * 2;
  float* pbuf = (float*)w; w += (size_t)2 * PBPAR * 4;               // 3 MB partials
  // ---- zero region ----
  char* zstart = w;
  bf16* extra = (bf16*)w; w += 2 * SLOTE * 2;   // h4 slots 0,1 (slot 0 must be 0)
  bf16* h2a   = (bf16*)w; w += SLOTE * 2;
  bf16* h2b   = (bf16*)w; w += SLOTE * 2;
  float* ss_li = (float*)w; w += (size_t)(TSTEPS + 1) * BATCH * 4;
  float* ss_bp = (float*)w; w += (size_t)(TSTEPS + 1) * BATCH * 4;
  unsigned* flags = (unsigned*)w; w += (size_t)64 * GSTRIDE * 4;  // per-kq flags
  unsigned* bar = (unsigned*)w; w += (size_t)32 * GSTRIDE * 4;    // done + rel
  int zero_u32 = (int)((w - zstart) / 4);

  cvt_bf16<<<4096, 256, 0, stream>>>(x, xbf, (BATCH * TSTEPS * INDIM) / 4);
  cvt_bf16<<<1024, 256, 0, stream>>>(W_in, winb, (XDIM * INDIM) / 4);
  cvt_bf16<<<32768, 256, 0, stream>>>(W_h, whb, (4 * XDIM * 2 * XDIM) / 4);
  cvt_bf16<<<512, 256, 0, stream>>>(W_out, woutb, (OUTDIM * XDIM) / 4);
  zero32<<<(zero_u32 + 255) / 256, 256, 0, stream>>>((uint32_t*)zstart, zero_u32);
  h0_gemm<<<dim3(16, 128), 256, 0, stream>>>(xbf, winb, b_in, act_ids, h0);

  StepParams sp;
  sp.h0 = h0;
  sp.extra = extra;
  sp.h1 = h1;
  sp.h2a = h2a;
  sp.h2b = h2b;
  sp.h3 = h3;
  sp.whb = whb;
  sp.b_h = b_h;
  sp.acts = act_ids;
  sp.ss_li = ss_li;
  sp.ss_bp = ss_bp;
  sp.pbuf = pbuf;
  sp.flags = flags;
  sp.bar = bar;
  void* kp[] = {&sp};
  (void)hipLaunchCooperativeKernel((const void*)step_loop, dim3(NBLOCKS),
                                   dim3(512), kp, 0, stream);

  // all y_t in one GEMM over the stored h4 slots
  ybat_gemm<<<dim3(2, TSTEPS), 256, 0, stream>>>(
      extra, h0, woutb, b_out, out_act, out);
}

// Round 12
// 9363.493 us; speedup vs baseline: 1.0062x; 1.0062x over previous
//
#include <hip/hip_runtime.h>
#include <stdint.h>

// ---------------------------------------------------------------------------
// ComplexApproximateBNN, round 15. R14 (A2 run-ahead) regressed -> phase is
// serial-LATENCY-bound on the sync chain, not bandwidth-bound. R15 = exact
// R13 (best, 8597us) + ONE change: the release fan-out loses its middleman.
// R13 tail: combiner->done RMW -> leader polls done -> leader ticks rel ->
// member polls rel (4 serialized MALL hops). R15: each combiner's lanes 0-7
// tick ALL 8 padded rel lines directly (one divergent atomic instruction);
// members poll their line >= 64*ph. 2 hops. done counter + leader deleted.
// Micro: combiner's ss_in bypass-load hoisted before its flag wait.
// Everything else byte-identical to R13 (W-stationary 128 VGPR pinned,
// RMW-exchange writes, relaxed agent atomic loads, zero fences).
// ---------------------------------------------------------------------------

typedef __bf16 bf16;
typedef __attribute__((ext_vector_type(8))) __bf16 bf16x8;
typedef __attribute__((ext_vector_type(4))) float f32x4;

#define BATCH 64
#define TSTEPS 128
#define INDIM 512
#define XDIM 2048
#define OUTDIM 256
#define SLOTE ((size_t)BATCH * XDIM)  // elements per [b][2048] slot
#define NBLOCKS 256
#define GSTRIDE 64                    // u32 stride between counters = 256 B
#define PBPAR ((size_t)3 * BATCH * XDIM)  // one parity's partial region (f32)

__device__ __forceinline__ float apply_act(float h, int id) {
  switch (id) {
    case 0: return fmaxf(h, 0.0f);                       // relu
    case 1: return 1.0f / (1.0f + __expf(-h));           // sigmoid
    case 2: return tanhf(h);                             // tanh
    case 3: return h >= 0.0f ? h : 0.1f * h;             // leaky 0.1
    default: {                                           // selu
      const float sc = 1.0507009873554805f;
      const float al = 1.6732632423543772f;
      return h > 0.0f ? sc * h : sc * al * (__expf(h) - 1.0f);
    }
  }
}

// Agent-coherent 16B load as 2x8B relaxed atomic loads (proven R5/R9-R14).
__device__ __forceinline__ bf16x8 cload(const bf16* p) {
  union { unsigned long long q[2]; bf16x8 v; } u;
  const unsigned long long* qp = (const unsigned long long*)p;
  u.q[0] = __hip_atomic_load(qp, __ATOMIC_RELAXED, __HIP_MEMORY_SCOPE_AGENT);
  u.q[1] = __hip_atomic_load(qp + 1, __ATOMIC_RELAXED, __HIP_MEMORY_SCOPE_AGENT);
  return u.v;
}

// Coherent 8B store via atomic exchange (RMW at coherence point; proven R9).
__device__ __forceinline__ void cstore8(unsigned long long* p,
                                        unsigned long long v) {
  unsigned long long old = __hip_atomic_exchange(p, v, __ATOMIC_RELAXED,
                                                 __HIP_MEMORY_SCOPE_AGENT);
  asm volatile("" :: "v"(old));
}

__device__ __forceinline__ unsigned long long cload8(
    const unsigned long long* p) {
  return __hip_atomic_load(p, __ATOMIC_RELAXED, __HIP_MEMORY_SCOPE_AGENT);
}

// Phase-completion wait: every combiner ticks all 8 rel lines (lanes 0-7),
// so rel[g] >= 64*ph certifies all 64 combiners of phase ph finished.
// Members poll only their group's padded line (31 pollers/line, storm-free).
__device__ __forceinline__ void phase_wait(unsigned* bars, int bid,
                                           unsigned ph) {
  if (threadIdx.x == 0) {
    unsigned* rel = bars + (size_t)(9 + (bid >> 5)) * GSTRIDE;
    while (__hip_atomic_load(rel, __ATOMIC_RELAXED,
                             __HIP_MEMORY_SCOPE_AGENT) < 64u * ph) {
      __builtin_amdgcn_s_sleep(2);
    }
  }
  __syncthreads();
}

// One layer phase, W-stationary (R13 body). Block (nt = 32-col tile, kq =
// K-quarter). kq>=1: publish partial (parity-buffered u64 exchanges) + flag.
// kq=0: wait 3 flags, read partials, combine lo + scale*hi + bias, act, ss,
// store h, then lanes 0-7 tick the 8 rel lines (direct release broadcast).
template <bool SCALE_A2, bool EMIT_SS, bool PLAIN_A1>
__device__ __forceinline__ void layer_phase(
    const int tid, const int nt, const int kq,
    const bf16* __restrict__ A1, const bf16* __restrict__ A2,
    const bf16x8 (&wf)[2][4], const float* __restrict__ bias,
    const int* __restrict__ acts, const float* __restrict__ ss_in,
    float* __restrict__ ss_out, bf16* __restrict__ outb,
    float* __restrict__ pbuf, unsigned* __restrict__ flags,
    unsigned* __restrict__ bars, const unsigned ph,
    float (&red)[8][64][33]) {
  const int lane = tid & 63;
  const int w = tid >> 6;        // 0..7 : 128-k slice within the K-quarter
  const int l15 = lane & 15;
  const int kb8 = (lane >> 4) * 8;
  const int q4 = lane >> 4;

  const bf16* As = (kq >= 2) ? A2 : A1;
  const int koff = (kq & 1) * 1024 + w * 128;
  const bf16* ap = As + (size_t)l15 * 2048 + koff + kb8;

  f32x4 acc[4][2];
  const f32x4 zero = {0.f, 0.f, 0.f, 0.f};
#pragma unroll
  for (int mt = 0; mt < 4; mt++) {
    acc[mt][0] = zero;
    acc[mt][1] = zero;
  }

  const bool plain = PLAIN_A1 && (kq < 2);
#pragma unroll
  for (int ks = 0; ks < 4; ks++) {
#pragma unroll
    for (int mt = 0; mt < 4; mt++) {
      const bf16* aptr = ap + (size_t)mt * 16 * 2048 + ks * 32;
      bf16x8 a = plain ? *(const bf16x8*)aptr : cload(aptr);
      acc[mt][0] = __builtin_amdgcn_mfma_f32_16x16x32_bf16(a, wf[0][ks], acc[mt][0], 0, 0, 0);
      acc[mt][1] = __builtin_amdgcn_mfma_f32_16x16x32_bf16(a, wf[1][ks], acc[mt][1], 0, 0, 0);
    }
  }

#pragma unroll
  for (int mt = 0; mt < 4; mt++)
#pragma unroll
    for (int n2 = 0; n2 < 2; n2++)
#pragma unroll
      for (int r = 0; r < 4; r++)
        red[w][mt * 16 + q4 * 4 + r][n2 * 16 + l15] = acc[mt][n2][r];
  __syncthreads();

  // per-thread ownership: row = tid>>3 (0..63), cols c4..c4+3
  const int row = tid >> 3;
  const int c4 = (tid & 7) * 4;
  float v[4];
#pragma unroll
  for (int j = 0; j < 4; j++) {
    float s = 0.f;
#pragma unroll
    for (int ww = 0; ww < 8; ww++) s += red[ww][row][c4 + j];
    v[j] = s;
  }

  float* pbase = pbuf + (size_t)(ph & 1) * PBPAR;
  const size_t pidx = ((size_t)row) * XDIM + nt * 32 + c4;
  if (kq != 0) {
    // writer: publish partial for this K-quarter (parity-buffered)
    float* pb = pbase + (size_t)(kq - 1) * BATCH * XDIM + pidx;
    union { float f[2]; unsigned long long u; } pk;
    pk.f[0] = v[0]; pk.f[1] = v[1];
    cstore8((unsigned long long*)pb, pk.u);
    pk.f[0] = v[2]; pk.f[1] = v[3];
    cstore8((unsigned long long*)(pb + 2), pk.u);
    __syncthreads();  // drain exchanges (vmcnt 0) before flag
    if (tid == 0) {
      __hip_atomic_fetch_add(flags + (size_t)nt * GSTRIDE, 1u,
                             __ATOMIC_RELAXED, __HIP_MEMORY_SCOPE_AGENT);
    }
  } else {
    // combiner: hoist the ss_in bypass load so its RTT hides under the
    // flag poll; then wait the 3 writer flags.
    float scale = 1.0f;
    if (SCALE_A2) {
      float ssv = __hip_atomic_load(ss_in + row, __ATOMIC_RELAXED,
                                    __HIP_MEMORY_SCOPE_AGENT);
      scale = 1.0f / fmaxf(sqrtf(ssv), 1e-12f);
    }
    if (tid == 0) {
      while (__hip_atomic_load(flags + (size_t)nt * GSTRIDE, __ATOMIC_RELAXED,
                               __HIP_MEMORY_SCOPE_AGENT) < 3u * ph) {
        __builtin_amdgcn_s_sleep(1);
      }
    }
    __syncthreads();
    float p1[4], p2[4], p3[4];
#pragma unroll
    for (int h = 0; h < 2; h++) {
      union { unsigned long long u; float f[2]; } u1, u2, u3;
      const unsigned long long* b1 =
          (const unsigned long long*)(pbase + pidx) + h;
      u1.u = cload8(b1);
      u2.u = cload8(b1 + (size_t)BATCH * XDIM / 2);
      u3.u = cload8(b1 + (size_t)BATCH * XDIM);
      p1[h * 2] = u1.f[0]; p1[h * 2 + 1] = u1.f[1];
      p2[h * 2] = u2.f[0]; p2[h * 2 + 1] = u2.f[1];
      p3[h * 2] = u3.f[0]; p3[h * 2 + 1] = u3.f[1];
    }
    const int cg = nt * 32 + c4;
    union { bf16 b[4]; unsigned long long u; } hk;
    float ssl = 0.f;
#pragma unroll
    for (int j = 0; j < 4; j++) {
      float lo = v[j] + p1[j];
      float hi = p2[j] + p3[j];
      float pre = (SCALE_A2 ? (lo + scale * hi) : (lo + hi)) + bias[cg + j];
      float av = apply_act(pre, acts[cg + j]);
      hk.b[j] = (bf16)av;
      ssl += av * av;
    }
    if (EMIT_SS) {
      ssl += __shfl_xor(ssl, 1);
      ssl += __shfl_xor(ssl, 2);
      ssl += __shfl_xor(ssl, 4);
      if ((tid & 7) == 0) atomicAdd(ss_out + row, ssl);
    }
    cstore8((unsigned long long*)(outb + (size_t)row * XDIM + cg), hk.u);
    __syncthreads();  // drain h exchanges + ss atomics before release
    if (tid < 8) {
      // direct release broadcast: 8 lanes tick the 8 padded rel lines
      __hip_atomic_fetch_add(bars + (size_t)(9 + tid) * GSTRIDE, 1u,
                             __ATOMIC_RELAXED, __HIP_MEMORY_SCOPE_AGENT);
    }
  }
}

struct StepParams {
  bf16* h0;           // [128][64][2048], slices also reused as h4 slots 2..
  bf16* extra;        // h4 slots 0,1
  bf16* h1;
  bf16* h2a;
  bf16* h2b;
  bf16* h3;
  const bf16* whb;    // [4][2048][4096]
  const float* b_h;   // [4][2048]
  const int* acts;    // [5][2048]
  float* ss_li;       // [(T+1)*64]
  float* ss_bp;       // [(T+1)*64]
  float* pbuf;        // [2 parity][3][64][2048] f32 K-quarter partials
  unsigned* flags;    // [64*GSTRIDE] combine flags
  unsigned* bar;      // rel lines (zeroed), 32*GSTRIDE u32s
};

__global__ __launch_bounds__(512, 2) void step_loop(StepParams p) {
  __shared__ float red[8][64][33];
  const int tid = threadIdx.x;
  const int bid = blockIdx.x;
  const int nt = bid & 63;    // 32-col n-tile
  const int kq = bid >> 6;    // K-quarter (0,1: A1 halves; 2,3: A2 halves)
  const int lane = tid & 63;
  const int w = tid >> 6;
  const int l15 = lane & 15;
  const int kb8 = (lane >> 4) * 8;
  const size_t wstr = (size_t)XDIM * 2 * XDIM;

  // One-time W preload: 4 layers x 2 ntiles x 4 ksteps x bf16x8 = 128 VGPR.
  const bf16* wb = p.whb + (size_t)(nt * 32 + l15) * 4096 + kq * 1024 +
                   w * 128 + kb8;
  bf16x8 wf0[2][4], wf1[2][4], wf2[2][4], wf3[2][4];
#pragma unroll
  for (int n2 = 0; n2 < 2; n2++) {
#pragma unroll
    for (int ks = 0; ks < 4; ks++) {
      const bf16* q = wb + (size_t)n2 * 16 * 4096 + ks * 32;
      wf0[n2][ks] = *(const bf16x8*)q;
      wf1[n2][ks] = *(const bf16x8*)(q + wstr);
      wf2[n2][ks] = *(const bf16x8*)(q + 2 * wstr);
      wf3[n2][ks] = *(const bf16x8*)(q + 3 * wstr);
    }
  }

  unsigned ph = 0;
  for (int t = 0; t < TSTEPS; t++) {
    // Pin W fragments: opaque asm touch defeats rematerialization/reload.
#pragma unroll
    for (int n2 = 0; n2 < 2; n2++)
#pragma unroll
      for (int ks = 0; ks < 4; ks++) {
        asm volatile("" : "+v"(wf0[n2][ks]), "+v"(wf1[n2][ks]),
                          "+v"(wf2[n2][ks]), "+v"(wf3[n2][ks]));
      }

    const bf16* h4t = (t < 2) ? p.extra + (size_t)t * SLOTE
                              : p.h0 + (size_t)(t - 2) * SLOTE;
    bf16* h4n = (t + 1 < 2) ? p.extra + (size_t)(t + 1) * SLOTE
                            : p.h0 + (size_t)(t - 1) * SLOTE;
    bf16* h2n = (t & 1) ? p.h2b : p.h2a;
    const bf16* h2o = (t & 1) ? p.h2a : p.h2b;

    // h1 = act([h0_t, norm(h4_t)] @ W0^T + b0)   (h0 pristine -> plain)
    ++ph;
    layer_phase<true, false, true>(tid, nt, kq, p.h0 + (size_t)t * SLOTE, h4t,
                                   wf0, p.b_h, p.acts + XDIM,
                                   p.ss_bp + t * BATCH, nullptr, p.h1,
                                   p.pbuf, p.flags, p.bar, ph, red);
    phase_wait(p.bar, bid, ph);

    // h2 = act([h1, norm(h2_old)] @ W1^T + b1); emit ss_li[t+1]
    ++ph;
    layer_phase<true, true, false>(tid, nt, kq, p.h1, h2o, wf1, p.b_h + XDIM,
                                   p.acts + 2 * XDIM, p.ss_li + t * BATCH,
                                   p.ss_li + (t + 1) * BATCH, h2n,
                                   p.pbuf, p.flags, p.bar, ph, red);
    phase_wait(p.bar, bid, ph);

    // h3 = act([h2, h1] @ W2^T + b2)
    ++ph;
    layer_phase<false, false, false>(tid, nt, kq, h2n, p.h1, wf2,
                                     p.b_h + 2 * XDIM, p.acts + 3 * XDIM,
                                     nullptr, nullptr, p.h3,
                                     p.pbuf, p.flags, p.bar, ph, red);
    phase_wait(p.bar, bid, ph);

    // h4 = act([h3, h2] @ W3^T + b3) -> slot t+1; emit ss_bp[t+1]
    ++ph;
    layer_phase<false, true, false>(tid, nt, kq, p.h3, h2n, wf3,
                                    p.b_h + 3 * XDIM, p.acts + 4 * XDIM,
                                    nullptr, p.ss_bp + (t + 1) * BATCH, h4n,
                                    p.pbuf, p.flags, p.bar, ph, red);
    phase_wait(p.bar, bid, ph);
  }
}

// h0 precompute: [8192,512]@[512->2048], rows r=b*128+t remapped to [t][b][n]
__global__ __launch_bounds__(256) void h0_gemm(
    const bf16* __restrict__ A, const bf16* __restrict__ W,
    const float* __restrict__ bias, const int* __restrict__ acts,
    bf16* __restrict__ outp) {
  const int tid = threadIdx.x;
  const int lane = tid & 63;
  const int wv = tid >> 6;
  const int wm = (wv & 1) * 32;
  const int wn = (wv >> 1) * 64;
  const int nblk = blockIdx.x * 128;
  const int mblk = blockIdx.y * 64;
  const int l15 = lane & 15;
  const int kb8 = (lane >> 4) * 8;

  f32x4 acc[2][4];
  const f32x4 zero = {0.f, 0.f, 0.f, 0.f};
#pragma unroll
  for (int i = 0; i < 2; i++)
#pragma unroll
    for (int j = 0; j < 4; j++) acc[i][j] = zero;

  for (int kt = 0; kt < INDIM; kt += 32) {
    bf16x8 a[2], b[4];
#pragma unroll
    for (int mt = 0; mt < 2; mt++) {
      int m = mblk + wm + mt * 16 + l15;
      a[mt] = *(const bf16x8*)(A + (size_t)m * INDIM + kt + kb8);
    }
#pragma unroll
    for (int nt = 0; nt < 4; nt++) {
      int n = nblk + wn + nt * 16 + l15;
      b[nt] = *(const bf16x8*)(W + (size_t)n * INDIM + kt + kb8);
    }
#pragma unroll
    for (int mt = 0; mt < 2; mt++)
#pragma unroll
      for (int nt = 0; nt < 4; nt++)
        acc[mt][nt] = __builtin_amdgcn_mfma_f32_16x16x32_bf16(a[mt], b[nt], acc[mt][nt], 0, 0, 0);
  }

#pragma unroll
  for (int mt = 0; mt < 2; mt++) {
#pragma unroll
    for (int nt = 0; nt < 4; nt++) {
      int n = nblk + wn + nt * 16 + l15;
      float bv = bias[n];
      int aid = acts[n];
#pragma unroll
      for (int rr = 0; rr < 4; rr++) {
        int m = wm + mt * 16 + (lane >> 4) * 4 + rr;
        float v = apply_act(acc[mt][nt][rr] + bv, aid);
        int rowg = mblk + m;  // = b*128 + t
        int bb = rowg >> 7;
        int tt = rowg & 127;
        outp[((size_t)tt * BATCH + bb) * XDIM + n] = (bf16)v;
      }
    }
  }
}

// batched output layer: for each t, y_t = act(h4slot(t+1) @ Wout^T + bout).
__global__ __launch_bounds__(256) void ybat_gemm(
    const bf16* __restrict__ extra, const bf16* __restrict__ h0,
    const bf16* __restrict__ Wout, const float* __restrict__ bout,
    const int* __restrict__ oact, float* __restrict__ out) {
  const int t = blockIdx.y;
  const int s = t + 1;
  const bf16* A = (s < 2) ? (extra + (size_t)s * SLOTE)
                          : (h0 + (size_t)(s - 2) * SLOTE);
  const int tid = threadIdx.x;
  const int lane = tid & 63;
  const int wv = tid >> 6;
  const int wm = (wv & 1) * 32;
  const int wn = (wv >> 1) * 64;
  const int nblk = blockIdx.x * 128;
  const int l15 = lane & 15;
  const int kb8 = (lane >> 4) * 8;

  f32x4 acc[2][4];
  const f32x4 zero = {0.f, 0.f, 0.f, 0.f};
#pragma unroll
  for (int i = 0; i < 2; i++)
#pragma unroll
    for (int j = 0; j < 4; j++) acc[i][j] = zero;

  for (int kt = 0; kt < XDIM; kt += 32) {
    bf16x8 a[2], b[4];
#pragma unroll
    for (int mt = 0; mt < 2; mt++) {
      int m = wm + mt * 16 + l15;
      a[mt] = *(const bf16x8*)(A + (size_t)m * XDIM + kt + kb8);
    }
#pragma unroll
    for (int nt = 0; nt < 4; nt++) {
      int n = nblk + wn + nt * 16 + l15;
      b[nt] = *(const bf16x8*)(Wout + (size_t)n * XDIM + kt + kb8);
    }
#pragma unroll
    for (int mt = 0; mt < 2; mt++)
#pragma unroll
      for (int nt = 0; nt < 4; nt++)
        acc[mt][nt] = __builtin_amdgcn_mfma_f32_16x16x32_bf16(a[mt], b[nt], acc[mt][nt], 0, 0, 0);
  }

#pragma unroll
  for (int mt = 0; mt < 2; mt++) {
#pragma unroll
    for (int nt = 0; nt < 4; nt++) {
      int n = nblk + wn + nt * 16 + l15;
      float bv = bout[n];
      int aid = oact[n];
#pragma unroll
      for (int rr = 0; rr < 4; rr++) {
        int b = wm + mt * 16 + (lane >> 4) * 4 + rr;  // batch row
        float v = apply_act(acc[mt][nt][rr] + bv, aid);
        out[((size_t)b * TSTEPS + t) * OUTDIM + n] = v;
      }
    }
  }
}

__global__ __launch_bounds__(256) void cvt_bf16(
    const float* __restrict__ in, bf16* __restrict__ out, int n4) {
  int i = blockIdx.x * 256 + threadIdx.x;
  if (i < n4) {
    float4 v = ((const float4*)in)[i];
    union { bf16 b[4]; unsigned long long u; } pk;
    pk.b[0] = (bf16)v.x;
    pk.b[1] = (bf16)v.y;
    pk.b[2] = (bf16)v.z;
    pk.b[3] = (bf16)v.w;
    ((unsigned long long*)out)[i] = pk.u;
  }
}

__global__ __launch_bounds__(256) void zero32(uint32_t* __restrict__ p, int n) {
  int i = blockIdx.x * 256 + threadIdx.x;
  if (i < n) p[i] = 0u;
}

extern "C" void kernel_launch(void* const* d_in, const int* in_sizes, int n_in,
                              void* d_out, int out_size, void* d_ws, size_t ws_size,
                              hipStream_t stream) {
  const float* x     = (const float*)d_in[0];   // [64,128,512]
  const float* W_in  = (const float*)d_in[1];   // [2048,512]
  const float* b_in  = (const float*)d_in[2];   // [2048]
  const float* W_h   = (const float*)d_in[3];   // [4,2048,4096]
  const float* b_h   = (const float*)d_in[4];   // [4,2048]
  const float* W_out = (const float*)d_in[5];   // [256,2048]
  const float* b_out = (const float*)d_in[6];   // [256]
  const int* act_ids = (const int*)d_in[7];     // [5,2048]
  const int* out_act = (const int*)d_in[8];     // [256]
  float* out = (float*)d_out;                   // [64,128,256]

  char* w = (char*)d_ws;
  bf16* xbf   = (bf16*)w; w += (size_t)BATCH * TSTEPS * INDIM * 2;   // 8 MB
  bf16* winb  = (bf16*)w; w += (size_t)XDIM * INDIM * 2;             // 2 MB
  bf16* whb   = (bf16*)w; w += (size_t)4 * XDIM * (2 * XDIM) * 2;    // 64 MB
  bf16* woutb = (bf16*)w; w += (size_t)OUTDIM * XDIM * 2;            // 1 MB
  bf16* h0    = (bf16*)w; w += (size_t)TSTEPS * SLOTE * 2;           // 32 MB (doubles as h4 slots 2..)
  bf16* h1    = (bf16*)w; w += SLOTE * 2;
  bf16* h3    = (bf16*)w; w += SLOTE * 2;
  float* pbuf = (float*)w; w += (size_t)2 * PBPAR * 4;               // 3 MB partials
  // ---- zero region ----
  char* zstart = w;
  bf16* extra = (bf16*)w; w += 2 * SLOTE * 2;   // h4 slots 0,1 (slot 0 must be 0)
  bf16* h2a   = (bf16*)w; w += SLOTE * 2;
  bf16* h2b   = (bf16*)w; w += SLOTE * 2;
  float* ss_li = (float*)w; w += (size_t)(TSTEPS + 1) * BATCH * 4;
  float* ss_bp = (float*)w; w += (size_t)(TSTEPS + 1) * BATCH * 4;
  unsigned* flags = (unsigned*)w; w += (size_t)64 * GSTRIDE * 4;  // combine flags
  unsigned* bar = (unsigned*)w; w += (size_t)32 * GSTRIDE * 4;    // rel lines
  int zero_u32 = (int)((w - zstart) / 4);

  cvt_bf16<<<4096, 256, 0, stream>>>(x, xbf, (BATCH * TSTEPS * INDIM) / 4);
  cvt_bf16<<<1024, 256, 0, stream>>>(W_in, winb, (XDIM * INDIM) / 4);
  cvt_bf16<<<32768, 256, 0, stream>>>(W_h, whb, (4 * XDIM * 2 * XDIM) / 4);
  cvt_bf16<<<512, 256, 0, stream>>>(W_out, woutb, (OUTDIM * XDIM) / 4);
  zero32<<<(zero_u32 + 255) / 256, 256, 0, stream>>>((uint32_t*)zstart, zero_u32);
  h0_gemm<<<dim3(16, 128), 256, 0, stream>>>(xbf, winb, b_in, act_ids, h0);

  StepParams sp;
  sp.h0 = h0;
  sp.extra = extra;
  sp.h1 = h1;
  sp.h2a = h2a;
  sp.h2b = h2b;
  sp.h3 = h3;
  sp.whb = whb;
  sp.b_h = b_h;
  sp.acts = act_ids;
  sp.ss_li = ss_li;
  sp.ss_bp = ss_bp;
  sp.pbuf = pbuf;
  sp.flags = flags;
  sp.bar = bar;
  void* kp[] = {&sp};
  (void)hipLaunchCooperativeKernel((const void*)step_loop, dim3(NBLOCKS),
                                   dim3(512), kp, 0, stream);

  // all y_t in one GEMM over the stored h4 slots
  ybat_gemm<<<dim3(2, TSTEPS), 256, 0, stream>>>(
      extra, h0, woutb, b_out, out_act, out);
}